// Round 12
// baseline (285.072 us; speedup 1.0000x reference)
//
#include <hip/hip_runtime.h>
#include <hip/hip_cooperative_groups.h>
#include <stdint.h>

namespace cg = cooperative_groups;

#define B_ 16
#define N_ 8400
#define M_ 128
#define OUT4_ 2889600   // B*N*86 floats / 4 per float4 (entire output)
#define ZPER_ 1411      // ceil(OUT4_/2048)

// IoU exactly per reference op order (no fma contraction).
__device__ __forceinline__ float iou_box(float ax1, float ay1, float ax2, float ay2,
                                         float bx1, float by1, float bx2, float by2) {
    float area1 = __fmul_rn(__fsub_rn(ax2, ax1), __fsub_rn(ay2, ay1));
    float area2 = __fmul_rn(__fsub_rn(bx2, bx1), __fsub_rn(by2, by1));
    float ix1 = fmaxf(ax1, bx1), iy1 = fmaxf(ay1, by1);
    float ix2 = fminf(ax2, bx2), iy2 = fminf(ay2, by2);
    float iw = fmaxf(__fsub_rn(ix2, ix1), 0.0f);
    float ih = fmaxf(__fsub_rn(iy2, iy1), 0.0f);
    float inter = __fmul_rn(iw, ih);
    float uni = __fsub_rn(__fadd_rn(area1, area2), inter);
    return __fdiv_rn(inter, __fadd_rn(uni, 1e-9f));
}

// ONE cooperative dispatch, 2048 blocks x 256 (= exactly 8 blocks/CU x 256 CU;
// __launch_bounds__(256,8) caps VGPR<=64 so the grid is co-resident).
// Block g = GT g.
//  Phase A: threads 0..191 = R10/R11-PROVEN assign (wave w = level w, 64-lane
//           bitonic u64 top-9, odd-even index sort, 27 iou/cin, serial thr
//           chain, 0xC-packed atomicMax into ws). Threads 192..255 zero a
//           1/2048 slice of the ENTIRE output (labels|bboxes|scores|fg) —
//           data-independent of ws, overlaps assign compute.
//  grid.sync()
//  Phase B: thread t<66 decodes anchor g*66+t (device-scope atomic read of
//           ws — sidesteps cross-XCD L2 staleness) and rewrites ONLY fg
//           anchors' label/bbox/fg/score-slot (R7-proven decode).
// ws is NOT pre-zeroed (harness poisons 0xAA..): 0xC pack beats poison,
// preserves iou-then-smallest-m order; fg <=> top 2 bits == 11.
__global__ __launch_bounds__(256, 8) void fused_coop_kernel(
    const int* __restrict__ gt_labels,
    const float* __restrict__ gt_bboxes,
    const int* __restrict__ mask_gt,
    const float* __restrict__ pred_bboxes,
    const int* __restrict__ num_classes_p,
    unsigned long long* __restrict__ ws,
    float* __restrict__ out) {
    cg::grid_group grid = cg::this_grid();
    const int g = blockIdx.x;        // GT index 0..2047
    const int t = threadIdx.x;
    const bool activeGT = (mask_gt[g] != 0);   // is_pos &= mask_gt>0
    const int b = g >> 7;
    const int m = g & (M_ - 1);

    __shared__ int   s_idx[27];
    __shared__ float s_iou[27];
    __shared__ int   s_cin[27];
    __shared__ float s_thr;

    float gx1 = 0.f, gy1 = 0.f, gx2 = 0.f, gy2 = 0.f;
    if (activeGT) {
        const float4 gb = ((const float4*)gt_bboxes)[g];
        gx1 = gb.x; gy1 = gb.y; gx2 = gb.z; gy2 = gb.w;
    }

    if (t >= 192) {
        // ---- zero slice of the whole output (64 threads/block) ----
        float4* o4 = (float4*)out;
        const float4 z4 = make_float4(0.f, 0.f, 0.f, 0.f);
        const int base = g * ZPER_;
        for (int k = t - 192; k < ZPER_; k += 64) {
            const int i = base + k;
            if (i < OUT4_) o4[i] = z4;
        }
    } else if (activeGT) {
        // ---- assign phase A1: per-lane key + bitonic (verbatim proven) ----
        const int w = t >> 6;            // wave = level 0..2
        const int lane = t & 63;
        const float gcx = __fmul_rn(__fadd_rn(gx1, gx2), 0.5f);
        const float gcy = __fmul_rn(__fadd_rn(gy1, gy2), 0.5f);
        const float g2 = __fadd_rn(__fmul_rn(gcx, gcx), __fmul_rn(gcy, gcy));

        const int   size  = (w == 0) ? 80 : ((w == 1) ? 40 : 20);
        const int   start = (w == 0) ? 0 : ((w == 1) ? 6400 : 8000);
        const float st    = (w == 0) ? 8.0f : ((w == 1) ? 16.0f : 32.0f);
        const float inv   = (w == 0) ? 0.125f : ((w == 1) ? 0.0625f : 0.03125f);

        int jl = (int)floorf(gcx * inv - 0.5f) - 2;
        int il = (int)floorf(gcy * inv - 0.5f) - 2;
        jl = min(max(jl, 0), size - 6);
        il = min(max(il, 0), size - 6);

        unsigned long long key = ~0ULL;   // lanes 36-63 pad with +inf keys
        if (lane < 36) {
            const int wy = lane / 6;
            const int wx = lane - wy * 6;
            const int   i   = il + wy;
            const int   j   = jl + wx;
            const float acy = __fmul_rn(__fadd_rn((float)i, 0.5f), st);  // exact int
            const float acx = __fmul_rn(__fadd_rn((float)j, 0.5f), st);  // exact int
            const int   n   = start + i * size + j;
            float a2  = __fadd_rn(__fmul_rn(acx, acx), __fmul_rn(acy, acy));
            float dot = __fadd_rn(__fmul_rn(acx, gcx), __fmul_rn(acy, gcy));
            float d2  = __fsub_rn(__fadd_rn(a2, g2), __fmul_rn(2.0f, dot));
            float dist = __fsqrt_rn(fmaxf(d2, 0.0f));
            // key = (dist_bits, idx): tie -> lower index (lax.top_k semantics)
            key = ((unsigned long long)__float_as_uint(dist) << 32) | (unsigned)n;
        }

        // 64-lane bitonic sort ascending (exact u64 compares, proven R10/R11)
#pragma unroll
        for (int k = 2; k <= 64; k <<= 1) {
#pragma unroll
            for (int j = k >> 1; j > 0; j >>= 1) {
                unsigned long long other = __shfl_xor(key, j, 64);
                const bool up = ((lane & k) == 0);
                const bool keepMin = (((lane & j) == 0) == up);
                const unsigned long long mn = key < other ? key : other;
                const unsigned long long mx = key < other ? other : key;
                key = keepMin ? mn : mx;
            }
        }
        if (lane < 9) s_idx[w * 9 + lane] = (int)(key & 0xFFFFFFFFu);
    }
    __syncthreads();

    // ---- per-level index sort ascending (odd-even net, proven) ----
    if (activeGT && t < 3) {
        int v[9];
#pragma unroll
        for (int k = 0; k < 9; ++k) v[k] = s_idx[t * 9 + k];
#pragma unroll
        for (int rr = 0; rr < 9; ++rr) {
#pragma unroll
            for (int p = (rr & 1); p + 1 < 9; p += 2) {
                int lo = min(v[p], v[p + 1]);
                int hi = max(v[p], v[p + 1]);
                v[p] = lo; v[p + 1] = hi;
            }
        }
#pragma unroll
        for (int k = 0; k < 9; ++k) s_idx[t * 9 + k] = v[k];
    }
    __syncthreads();

    // ---- 27 iou/cin (verbatim proven chain) ----
    if (activeGT && t < 27) {
        const int   l      = t / 9;
        const int   size2  = (l == 0) ? 80 : ((l == 1) ? 40 : 20);
        const int   start2 = (l == 0) ? 0 : ((l == 1) ? 6400 : 8000);
        const float st2    = (l == 0) ? 8.0f : ((l == 1) ? 16.0f : 32.0f);
        const float half   = __fmul_rn(st2, 0.5f);
        const int n = s_idx[t];
        const int loc = n - start2;
        const int i = loc / size2;
        const int j = loc - i * size2;
        float acx = __fmul_rn(__fadd_rn((float)j, 0.5f), st2);
        float acy = __fmul_rn(__fadd_rn((float)i, 0.5f), st2);
        float ax1 = __fsub_rn(acx, half), ay1 = __fsub_rn(acy, half);
        float ax2 = __fadd_rn(acx, half), ay2 = __fadd_rn(acy, half);
        float iou = iou_box(ax1, ay1, ax2, ay2, gx1, gy1, gx2, gy2);
        s_iou[t] = iou;
        s_cin[t] = (acx >= gx1 && acx <= gx2 && acy >= gy1 && acy <= gy2) ? 1 : 0;
    }
    __syncthreads();

    // ---- thr: serial ascending-kk chain (verbatim proven) ----
    if (activeGT && t == 0) {
        float tot = 0.0f, tot2 = 0.0f;
#pragma unroll
        for (int kk = 0; kk < 27; ++kk) {
            const float iou = s_iou[kk];
            tot  = __fadd_rn(tot, iou);
            tot2 = __fadd_rn(tot2, __fmul_rn(iou, iou));
        }
        float mean = __fdiv_rn(tot, 27.0f);   // count is always exactly 27
        float sqm  = __fdiv_rn(tot2, 27.0f);
        float var  = __fsub_rn(sqm, __fmul_rn(mean, mean));
        float stdv = __fsqrt_rn(fmaxf(var, 0.0f));
        s_thr = __fadd_rn(mean, stdv);
    }
    __syncthreads();

    // ---- gate + scatter (verbatim 0xC pack, proven R6/R7/R10/R11) ----
    if (activeGT && t < 27) {
        const float iou = s_iou[t];
        if (s_cin[t] && iou >= s_thr) {
            // max-iou wins, tie -> smallest m (np argmax first-occurrence).
            // Positives have iou > 0 (center inside GT => inter > 0).
            unsigned long long packed =
                ((unsigned long long)(0xC0000000u | __float_as_uint(iou)) << 32) |
                (unsigned long long)(0xFFFFFFFFu - (unsigned)m);
            atomicMax(&ws[(size_t)b * N_ + s_idx[t]], packed);
        }
    }

    grid.sync();

    // ---- phase B: sparse finalize, 66 anchors per block ----
    const int C = num_classes_p[0];
    if (t < 66) {
        const int idx = g * 66 + t;
        if (idx < B_ * N_) {
            // device-scope atomic read: coherent vs other-XCD atomicMax.
            const unsigned long long w = atomicAdd(&ws[idx], 0ULL);
            if ((w >> 62) == 3ULL) {            // fg (poison 0xAA.. gives 0b10)
                const int bb_ = idx / N_;
                const unsigned mm = 0xFFFFFFFFu - (unsigned)(w & 0xFFFFFFFFu);
                const float a_iou = __uint_as_float((unsigned)((w >> 32) & 0x3FFFFFFFu));
                const int label = gt_labels[bb_ * M_ + (int)mm];
                const float* gg = gt_bboxes + ((size_t)bb_ * M_ + mm) * 4;
                float4 bbv;
                bbv.x = gg[0]; bbv.y = gg[1]; bbv.z = gg[2]; bbv.w = gg[3];
                const float* p = pred_bboxes + (size_t)idx * 4;
                float piou = iou_box(p[0], p[1], p[2], p[3], bbv.x, bbv.y, bbv.z, bbv.w);
                const float v = __fmul_rn(a_iou, piou);  // assigned_ious * pred_assigned
                out[idx] = (float)label;
                ((float4*)(out + (size_t)B_ * N_))[idx] = bbv;
                out[(size_t)B_ * N_ * 5 + (size_t)idx * C + label] = v;
                out[(size_t)B_ * N_ * (5 + C) + idx] = 1.0f;
            }
        }
    }
}

extern "C" void kernel_launch(void* const* d_in, const int* in_sizes, int n_in,
                              void* d_out, int out_size, void* d_ws, size_t ws_size,
                              hipStream_t stream) {
    const int*   gt_labels  = (const int*)d_in[1];
    const float* gt_bboxes  = (const float*)d_in[2];
    const int*   mask_gt    = (const int*)d_in[3];
    const float* pred       = (const float*)d_in[4];
    const int*   ncls       = (const int*)d_in[5];
    unsigned long long* ws  = (unsigned long long*)d_ws;
    float* out              = (float*)d_out;

    void* args[] = {(void*)&gt_labels, (void*)&gt_bboxes, (void*)&mask_gt,
                    (void*)&pred, (void*)&ncls, (void*)&ws, (void*)&out};
    hipLaunchCooperativeKernel((const void*)fused_coop_kernel,
                               dim3(B_ * M_), dim3(256), args, 0, stream);
}

// Round 13
// 83.169 us; speedup vs baseline: 3.4276x; 3.4276x over previous
//
#include <hip/hip_runtime.h>
#include <stdint.h>

#define B_ 16
#define N_ 8400
#define M_ 128
#define OUT4_ 2889600   // B*N*86 floats / 4 per float4 (entire output)
#define NB_   2560      // kernel-1 blocks
#define ZPER_ 1129      // ceil(OUT4_/NB_)

// IoU exactly per reference op order (no fma contraction).
__device__ __forceinline__ float iou_box(float ax1, float ay1, float ax2, float ay2,
                                         float bx1, float by1, float bx2, float by2) {
    float area1 = __fmul_rn(__fsub_rn(ax2, ax1), __fsub_rn(ay2, ay1));
    float area2 = __fmul_rn(__fsub_rn(bx2, bx1), __fsub_rn(by2, by1));
    float ix1 = fmaxf(ax1, bx1), iy1 = fmaxf(ay1, by1);
    float ix2 = fminf(ax2, bx2), iy2 = fminf(ay2, by2);
    float iw = fmaxf(__fsub_rn(ix2, ix1), 0.0f);
    float ih = fmaxf(__fsub_rn(iy2, iy1), 0.0f);
    float inter = __fmul_rn(iw, ih);
    float uni = __fsub_rn(__fadd_rn(area1, area2), inter);
    return __fdiv_rn(inter, __fadd_rn(uni, 1e-9f));
}

// Kernel 1, 2560 blocks x 256 (regular launch — cooperative failed R12):
//   blocks 0..2047: assign for GT g (R10/R11-PROVEN body verbatim: wave w =
//     level w on t<192, 64-lane bitonic u64 top-9, odd-even index sort,
//     27 iou/cin, serial ascending thr chain, 0xC-packed atomicMax into ws).
//     All 256 threads participate in barriers (t>=192 idle, no early return).
//   ALL 2560 blocks then zero a 1129-float4 slice of the ENTIRE output.
//     ~50% of assign blocks are mask-inactive and start storing immediately,
//     overlapping active blocks' compute; 2560-block write parallelism.
// ws is NOT pre-zeroed (harness poisons 0xAA..): 0xC pack beats poison,
// preserves iou-then-smallest-m order; fg <=> top 2 bits == 11.
__global__ __launch_bounds__(256) void assign_zero_kernel(
    const float* __restrict__ gt_bboxes,
    const int* __restrict__ mask_gt,
    unsigned long long* __restrict__ ws,
    float* __restrict__ out) {
    const int g = blockIdx.x;
    const int t = threadIdx.x;
    const bool doAssign = (g < 2048) && (mask_gt[g < 2048 ? g : 0] != 0);

    if (doAssign) {
        const int b = g >> 7;
        const int m = g & (M_ - 1);

        __shared__ int   s_idx[27];
        __shared__ float s_iou[27];
        __shared__ int   s_cin[27];
        __shared__ float s_thr;

        const float4 gb = ((const float4*)gt_bboxes)[g];
        const float gx1 = gb.x, gy1 = gb.y, gx2 = gb.z, gy2 = gb.w;
        const float gcx = __fmul_rn(__fadd_rn(gx1, gx2), 0.5f);
        const float gcy = __fmul_rn(__fadd_rn(gy1, gy2), 0.5f);
        const float g2 = __fadd_rn(__fmul_rn(gcx, gcx), __fmul_rn(gcy, gcy));

        if (t < 192) {
            // ---- per-lane key + bitonic (verbatim proven R10/R11) ----
            const int w = t >> 6;            // wave = level 0..2
            const int lane = t & 63;
            const int   size  = (w == 0) ? 80 : ((w == 1) ? 40 : 20);
            const int   start = (w == 0) ? 0 : ((w == 1) ? 6400 : 8000);
            const float st    = (w == 0) ? 8.0f : ((w == 1) ? 16.0f : 32.0f);
            const float inv   = (w == 0) ? 0.125f : ((w == 1) ? 0.0625f : 0.03125f);

            int jl = (int)floorf(gcx * inv - 0.5f) - 2;
            int il = (int)floorf(gcy * inv - 0.5f) - 2;
            jl = min(max(jl, 0), size - 6);
            il = min(max(il, 0), size - 6);

            unsigned long long key = ~0ULL;   // lanes 36-63 pad with +inf keys
            if (lane < 36) {
                const int wy = lane / 6;
                const int wx = lane - wy * 6;
                const int   i   = il + wy;
                const int   j   = jl + wx;
                const float acy = __fmul_rn(__fadd_rn((float)i, 0.5f), st);  // exact int
                const float acx = __fmul_rn(__fadd_rn((float)j, 0.5f), st);  // exact int
                const int   n   = start + i * size + j;
                float a2  = __fadd_rn(__fmul_rn(acx, acx), __fmul_rn(acy, acy));
                float dot = __fadd_rn(__fmul_rn(acx, gcx), __fmul_rn(acy, gcy));
                float d2  = __fsub_rn(__fadd_rn(a2, g2), __fmul_rn(2.0f, dot));
                float dist = __fsqrt_rn(fmaxf(d2, 0.0f));
                // key = (dist_bits, idx): tie -> lower index (lax.top_k)
                key = ((unsigned long long)__float_as_uint(dist) << 32) | (unsigned)n;
            }
#pragma unroll
            for (int k = 2; k <= 64; k <<= 1) {
#pragma unroll
                for (int j = k >> 1; j > 0; j >>= 1) {
                    unsigned long long other = __shfl_xor(key, j, 64);
                    const bool up = ((lane & k) == 0);
                    const bool keepMin = (((lane & j) == 0) == up);
                    const unsigned long long mn = key < other ? key : other;
                    const unsigned long long mx = key < other ? other : key;
                    key = keepMin ? mn : mx;
                }
            }
            if (lane < 9) s_idx[w * 9 + lane] = (int)(key & 0xFFFFFFFFu);
        }
        __syncthreads();

        // ---- per-level index sort ascending (odd-even net, proven) ----
        if (t < 3) {
            int v[9];
#pragma unroll
            for (int k = 0; k < 9; ++k) v[k] = s_idx[t * 9 + k];
#pragma unroll
            for (int rr = 0; rr < 9; ++rr) {
#pragma unroll
                for (int p = (rr & 1); p + 1 < 9; p += 2) {
                    int lo = min(v[p], v[p + 1]);
                    int hi = max(v[p], v[p + 1]);
                    v[p] = lo; v[p + 1] = hi;
                }
            }
#pragma unroll
            for (int k = 0; k < 9; ++k) s_idx[t * 9 + k] = v[k];
        }
        __syncthreads();

        // ---- 27 iou/cin (verbatim proven chain) ----
        if (t < 27) {
            const int   l      = t / 9;
            const int   size2  = (l == 0) ? 80 : ((l == 1) ? 40 : 20);
            const int   start2 = (l == 0) ? 0 : ((l == 1) ? 6400 : 8000);
            const float st2    = (l == 0) ? 8.0f : ((l == 1) ? 16.0f : 32.0f);
            const float half   = __fmul_rn(st2, 0.5f);
            const int n = s_idx[t];
            const int loc = n - start2;
            const int i = loc / size2;
            const int j = loc - i * size2;
            float acx = __fmul_rn(__fadd_rn((float)j, 0.5f), st2);
            float acy = __fmul_rn(__fadd_rn((float)i, 0.5f), st2);
            float ax1 = __fsub_rn(acx, half), ay1 = __fsub_rn(acy, half);
            float ax2 = __fadd_rn(acx, half), ay2 = __fadd_rn(acy, half);
            float iou = iou_box(ax1, ay1, ax2, ay2, gx1, gy1, gx2, gy2);
            s_iou[t] = iou;
            s_cin[t] = (acx >= gx1 && acx <= gx2 && acy >= gy1 && acy <= gy2) ? 1 : 0;
        }
        __syncthreads();

        // ---- thr: serial ascending-kk chain (verbatim proven) ----
        if (t == 0) {
            float tot = 0.0f, tot2 = 0.0f;
#pragma unroll
            for (int kk = 0; kk < 27; ++kk) {
                const float iou = s_iou[kk];
                tot  = __fadd_rn(tot, iou);
                tot2 = __fadd_rn(tot2, __fmul_rn(iou, iou));
            }
            float mean = __fdiv_rn(tot, 27.0f);   // count is always exactly 27
            float sqm  = __fdiv_rn(tot2, 27.0f);
            float var  = __fsub_rn(sqm, __fmul_rn(mean, mean));
            float stdv = __fsqrt_rn(fmaxf(var, 0.0f));
            s_thr = __fadd_rn(mean, stdv);
        }
        __syncthreads();

        // ---- gate + scatter (verbatim 0xC pack, proven) ----
        if (t < 27) {
            const float iou = s_iou[t];
            if (s_cin[t] && iou >= s_thr) {
                // max-iou wins, tie -> smallest m (np argmax first-occurrence).
                // Positives have iou > 0 (center inside GT => inter > 0).
                unsigned long long packed =
                    ((unsigned long long)(0xC0000000u | __float_as_uint(iou)) << 32) |
                    (unsigned long long)(0xFFFFFFFFu - (unsigned)m);
                atomicMax(&ws[(size_t)b * N_ + s_idx[t]], packed);
            }
        }
    }

    // ---- all blocks: zero this block's slice of the ENTIRE output ----
    {
        float4* o4 = (float4*)out;
        const float4 z4 = make_float4(0.f, 0.f, 0.f, 0.f);
        const int base = g * ZPER_;
#pragma unroll
        for (int k = 0; k < 5; ++k) {           // 5*256 = 1280 >= ZPER_
            const int i = base + t + k * 256;
            if (i < base + ZPER_ && i < OUT4_) o4[i] = z4;
        }
    }
}

// Kernel 2 (sparse finalize, R12-phase-B decode proven): per-anchor ws read;
// only fg anchors rewrite label/bbox/fg/score-slot. Background already
// correct (zeros) from kernel 1. 525 blocks x 256 = B*N exactly.
// out layout: labels[B*N] | bboxes[B*N*4] | scores[B*N*C] | fg[B*N]
__global__ __launch_bounds__(256) void finalize_kernel(
    const int* __restrict__ gt_labels,
    const float* __restrict__ gt_bboxes,
    const float* __restrict__ pred_bboxes,
    const int* __restrict__ num_classes_p,
    const unsigned long long* __restrict__ ws,
    float* __restrict__ out) {
    const int idx = blockIdx.x * 256 + threadIdx.x;
    const unsigned long long w = ws[idx];
    if ((w >> 62) != 3ULL) return;       // not fg (poison 0xAA.. gives 0b10)
    const int b = idx / N_;
    const int C = num_classes_p[0];

    const unsigned mm = 0xFFFFFFFFu - (unsigned)(w & 0xFFFFFFFFu);
    const float a_iou = __uint_as_float((unsigned)((w >> 32) & 0x3FFFFFFFu));
    const int label = gt_labels[b * M_ + (int)mm];
    const float* gg = gt_bboxes + ((size_t)b * M_ + mm) * 4;
    float4 bbv;
    bbv.x = gg[0]; bbv.y = gg[1]; bbv.z = gg[2]; bbv.w = gg[3];
    const float* p = pred_bboxes + (size_t)idx * 4;
    float piou = iou_box(p[0], p[1], p[2], p[3], bbv.x, bbv.y, bbv.z, bbv.w);
    const float v = __fmul_rn(a_iou, piou);  // assigned_ious * pred_assigned

    out[idx] = (float)label;
    ((float4*)(out + (size_t)B_ * N_))[idx] = bbv;
    out[(size_t)B_ * N_ * 5 + (size_t)idx * C + label] = v;
    out[(size_t)B_ * N_ * (5 + C) + idx] = 1.0f;
}

extern "C" void kernel_launch(void* const* d_in, const int* in_sizes, int n_in,
                              void* d_out, int out_size, void* d_ws, size_t ws_size,
                              hipStream_t stream) {
    const int*   gt_labels  = (const int*)d_in[1];
    const float* gt_bboxes  = (const float*)d_in[2];
    const int*   mask_gt    = (const int*)d_in[3];
    const float* pred       = (const float*)d_in[4];
    const int*   ncls       = (const int*)d_in[5];
    unsigned long long* ws  = (unsigned long long*)d_ws;
    float* out              = (float*)d_out;

    assign_zero_kernel<<<NB_, 256, 0, stream>>>(gt_bboxes, mask_gt, ws, out);
    finalize_kernel<<<(B_ * N_) / 256, 256, 0, stream>>>(
        gt_labels, gt_bboxes, pred, ncls, ws, out);
}